// Round 6
// baseline (161.628 us; speedup 1.0000x reference)
//
#include <hip/hip_runtime.h>

#define B        4
#define N        16384       // 2^14
#define NPOINT   2048        // 2^11
#define C        64
#define NSAMPLE  32
#define CH       (C + 3)     // 67 output channels
#define RADIUS2  0.01f
#define NCELL    1000        // 10^3 cells per batch (cell size = radius)
#define CSTRIDE  1032        // cell_start row stride (ints) >= NCELL+1
#define CAP      192         // per-query candidate cap (mean ~68, ~15 sigma)

typedef float vfloat4 __attribute__((ext_vector_type(4)));  // for nontemporal

__device__ __forceinline__ int clamp10(int v) {
    return v < 0 ? 0 : (v > 9 ? 9 : v);
}

// ---------------------------------------------------------------------------
// prep_kernel: ONE launch does the whole grid build AND the feature transpose.
//   blocks 0..3      : grid build for batch b = blockIdx.x, fully in LDS:
//                      histogram(1000) -> prefix scan -> cursor scatter.
//                      Outputs cs (cell starts, 0..1000) and sp (sorted pts).
//   blocks 4..1027   : transpose tile (64 cols) of features (B,C,N)->(B,N,C).
// grid = 4 + B*(N/64) = 1028, block = 256
// ---------------------------------------------------------------------------
__global__ __launch_bounds__(256) void prep_kernel(
    const float* __restrict__ xyz,   // (B,N,3)
    const float* __restrict__ f,     // (B,C,N)
    float* __restrict__ ft,          // (B,N,C)
    int* __restrict__ cs,            // (B, CSTRIDE) cell starts
    float4* __restrict__ sp)         // (B, N) cell-sorted points
{
    const int t = threadIdx.x;

    if (blockIdx.x < B) {
        // ---------------- grid build, one batch per block ----------------
        const int b = blockIdx.x;
        const float* xb = xyz + (size_t)b * N * 3;

        __shared__ int hist[1024];       // cells 1000..1023 stay 0
        __shared__ int wsum[256];

        hist[t] = 0; hist[256 + t] = 0; hist[512 + t] = 0; hist[768 + t] = 0;
        __syncthreads();

        // histogram (wave reads 64 consecutive points -> coalesced)
        for (int g = t; g < N; g += 256) {
            const int cx = clamp10((int)(xb[g * 3 + 0] * 10.f));
            const int cy = clamp10((int)(xb[g * 3 + 1] * 10.f));
            const int cz = clamp10((int)(xb[g * 3 + 2] * 10.f));
            atomicAdd(&hist[(cx * 10 + cy) * 10 + cz], 1);
        }
        __syncthreads();

        // exclusive prefix: 4 cells per thread + block scan of 256 sums
        const int h0 = hist[t * 4 + 0], h1 = hist[t * 4 + 1];
        const int h2 = hist[t * 4 + 2], h3 = hist[t * 4 + 3];
        wsum[t] = h0 + h1 + h2 + h3;
        __syncthreads();
        for (int off = 1; off < 256; off <<= 1) {
            const int u = (t >= off) ? wsum[t - off] : 0;
            __syncthreads();
            wsum[t] += u;
            __syncthreads();
        }
        const int base = (t == 0) ? 0 : wsum[t - 1];
        const int c0 = base, c1 = c0 + h0, c2 = c1 + h1, c3 = c2 + h2;
        __syncthreads();                 // everyone read hist before overwrite
        hist[t * 4 + 0] = c0;            // cursor = exclusive start
        hist[t * 4 + 1] = c1;
        hist[t * 4 + 2] = c2;
        hist[t * 4 + 3] = c3;
        int* csb = cs + b * CSTRIDE;
        csb[t * 4 + 0] = c0;             // covers 0..1023 (>=1001 needed)
        csb[t * 4 + 1] = c1;
        csb[t * 4 + 2] = c2;
        csb[t * 4 + 3] = c3;
        __syncthreads();

        // scatter via LDS cursors
        for (int g = t; g < N; g += 256) {
            const float x = xb[g * 3 + 0], y = xb[g * 3 + 1], z = xb[g * 3 + 2];
            const int cx = clamp10((int)(x * 10.f));
            const int cy = clamp10((int)(y * 10.f));
            const int cz = clamp10((int)(z * 10.f));
            const int pos = atomicAdd(&hist[(cx * 10 + cy) * 10 + cz], 1);
            sp[(b << 14) + pos] = make_float4(x, y, z, __int_as_float(g));
        }
    } else {
        // ---------------- feature transpose tile ----------------
        const int tt = blockIdx.x - B;       // 0..1023
        const int b  = tt >> 8;              // 256 tiles per batch
        const int n0 = (tt & 255) * 64;

        __shared__ float tile[64][65];
        const int r16 = t >> 4;              // 0..15
        const int x4  = t & 15;              // 0..15
        #pragma unroll
        for (int it = 0; it < 4; ++it) {
            const int cc = it * 16 + r16;
            const float4 v = *(const float4*)(f + ((size_t)b * C + cc) * N + n0 + x4 * 4);
            tile[cc][x4 * 4 + 0] = v.x;
            tile[cc][x4 * 4 + 1] = v.y;
            tile[cc][x4 * 4 + 2] = v.z;
            tile[cc][x4 * 4 + 3] = v.w;
        }
        __syncthreads();
        #pragma unroll
        for (int it = 0; it < 4; ++it) {
            const int nn = it * 16 + r16;
            float4 v;
            v.x = tile[x4 * 4 + 0][nn];
            v.y = tile[x4 * 4 + 1][nn];
            v.z = tile[x4 * 4 + 2][nn];
            v.w = tile[x4 * 4 + 3][nn];
            *(float4*)(ft + ((size_t)b * N + n0 + nn) * C + x4 * 4) = v;
        }
    }
}

// ---------------------------------------------------------------------------
// qg_kernel: fused ball query + grouping. One wave per query, 4 queries per
// 256-thr block. LDS ~39KB/block -> 4 blocks/CU = 16 waves/CU.
//   Query: order-free flattened scan of the 9 z-runs (bounds in SGPRs via
//          readlane), ballot-append candidates, rank-select restores index
//          order. Wave-private LDS -> __threadfence_block() only.
//   Group: gather 64 ch (float4 rows from transposed ft) + 3 rel-xyz into
//          padded LDS tile, then coalesced nontemporal float4 stores.
// ---------------------------------------------------------------------------
__global__ __launch_bounds__(256, 4) void qg_kernel(
    const float*  __restrict__ xyz,      // (B,N,3) (overflow fallback only)
    const float*  __restrict__ new_xyz,  // (B,NPOINT,3)
    const float*  __restrict__ ft,       // (B,N,C)
    const int*    __restrict__ cs,       // cell starts
    const float4* __restrict__ sp,       // cell-sorted points
    float* __restrict__ out_cnt,         // B*NPOINT
    float* __restrict__ out_feat)        // (B,CH,NPOINT,NSAMPLE)
{
    const int w = threadIdx.x >> 6;      // wave 0..3
    const int l = threadIdx.x & 63;
    const int q = blockIdx.x * 4 + w;    // 0..B*NPOINT-1
    const int b = q >> 11;
    const int j = q & (NPOINT - 1);

    __shared__ int   cand_s[4][CAP];
    __shared__ int   sidx_s[4][NSAMPLE];
    __shared__ float tile_s[4][CH * 33]; // stride 33 -> conflict-free
    int*   cand   = cand_s[w];
    int*   s_idx  = sidx_s[w];
    float* s_tile = tile_s[w];

    const float qx = new_xyz[q * 3 + 0];
    const float qy = new_xyz[q * 3 + 1];
    const float qz = new_xyz[q * 3 + 2];

    const int cx = clamp10((int)(qx * 10.f));
    const int cy = clamp10((int)(qy * 10.f));
    const int cz = clamp10((int)(qz * 10.f));
    const int z0 = cz > 0 ? cz - 1 : 0;
    const int z1 = cz < 9 ? cz + 1 : 9;

    // lanes 0..8 fetch the 9 run bounds (3x3 xy-cells, z contiguous)
    int sv = 0, ev = 0;
    if (l < 9) {
        const int xx = cx - 1 + l / 3;
        const int yy = cy - 1 + l % 3;
        if (xx >= 0 && xx <= 9 && yy >= 0 && yy <= 9) {
            const int cb = (xx * 10 + yy) * 10;
            sv = cs[b * CSTRIDE + cb + z0];
            ev = cs[b * CSTRIDE + cb + z1 + 1];
        }
    }
    const int len = ev - sv;

    // hoist run starts/lengths into uniform (SGPR) values
    int S[9], L[9];
    #pragma unroll
    for (int r = 0; r < 9; ++r) {
        S[r] = __builtin_amdgcn_readlane(sv, r);
        L[r] = __builtin_amdgcn_readlane(len, r);
    }
    int T = 0;
    #pragma unroll
    for (int r = 0; r < 9; ++r) T += L[r];

    const unsigned long long ltmask = (1ull << l) - 1ull;
    int total = 0, ncand = 0;
    for (int base = 0; base < T; base += 64) {
        const int wid = base + l;
        // select run + position for this work item (unrolled, register-only)
        int p = 0, acc = 0;
        bool act = false;
        #pragma unroll
        for (int r = 0; r < 9; ++r) {
            const int off = wid - acc;
            if (off >= 0 && off < L[r]) { p = S[r] + off; act = true; }
            acc += L[r];
        }
        float4 pt = make_float4(1e9f, 1e9f, 1e9f, 0.f);
        if (act) pt = sp[(b << 14) + p];
        const float dx = pt.x - qx, dy = pt.y - qy, dz = pt.z - qz;
        const float d2 = dx * dx + dy * dy + dz * dz;
        const bool in = act && (d2 < RADIUS2);
        const unsigned long long m = __ballot(in);
        if (in) {
            const int slot = ncand + __popcll(m & ltmask);
            if (slot < CAP) cand[slot] = __float_as_int(pt.w);
        }
        const int c = __popcll(m);
        total += c;
        ncand = ncand + c > CAP ? CAP : ncand + c;
    }

    int cntv;
    if (total > CAP) {
        // overflow (astronomically unlikely for uniform data): ordered rescan
        const float* xb = xyz + (size_t)b * N * 3;
        int cnt2 = 0;
        for (int base = 0; base < N; base += 64) {
            const int p = base + l;
            const float dx = xb[p * 3 + 0] - qx;
            const float dy = xb[p * 3 + 1] - qy;
            const float dz = xb[p * 3 + 2] - qz;
            const float d2 = dx * dx + dy * dy + dz * dz;
            const bool in = d2 < RADIUS2;
            const unsigned long long m = __ballot(in);
            if (in) {
                const int slot = cnt2 + __popcll(m & ltmask);
                if (slot < NSAMPLE) s_idx[slot] = p;
            }
            cnt2 += __popcll(m);
            if (cnt2 >= NSAMPLE) break;
        }
        cntv = cnt2 < NSAMPLE ? cnt2 : NSAMPLE;
        __threadfence_block();
    } else {
        __threadfence_block();           // cand[] appends visible to wave
        const int K = ncand;             // == total
        for (int c = l; c < K; c += 64) {
            const int v = cand[c];
            int rnk = 0;
            for (int i = 0; i < K; ++i) rnk += (cand[i] < v) ? 1 : 0;
            if (rnk < NSAMPLE) s_idx[rnk] = v;   // first-32 in index order
        }
        cntv = total < NSAMPLE ? total : NSAMPLE;
        __threadfence_block();
    }

    // fill unfound slots with first index (0 if none)
    if (l < NSAMPLE && l >= cntv) s_idx[l] = (cntv > 0) ? s_idx[0] : 0;
    __threadfence_block();

    if (l == 0) out_cnt[q] = (float)cntv;

    // ---- gather 64 feature channels: 16 lanes x 4 slots/pass, float4 rows --
    #pragma unroll
    for (int p = 0; p < 8; ++p) {
        const int k  = p * 4 + (l >> 4);         // slot 0..31
        const int c4 = l & 15;                   // float4 within 64 ch
        const int i  = s_idx[k];
        const float4 v = ((const float4*)(ft + ((size_t)b * N + i) * C))[c4];
        const int ch = 3 + c4 * 4;
        s_tile[(ch + 0) * 33 + k] = v.x;
        s_tile[(ch + 1) * 33 + k] = v.y;
        s_tile[(ch + 2) * 33 + k] = v.z;
        s_tile[(ch + 3) * 33 + k] = v.w;
    }
    // xyz channels 0..2 (relative coords)
    if (l < NSAMPLE) {
        const int i = s_idx[l];
        const float* xp = xyz + ((size_t)b * N + i) * 3;
        s_tile[0 * 33 + l] = xp[0] - qx;
        s_tile[1 * 33 + l] = xp[1] - qy;
        s_tile[2 * 33 + l] = xp[2] - qz;
    }
    __threadfence_block();

    // ---- coalesced nontemporal float4 stores (8 lanes per 128B line) ----
    vfloat4* of4 = (vfloat4*)out_feat;
    for (int e4 = l; e4 < CH * 8; e4 += 64) {
        const int ch = e4 >> 3;
        const int k4 = e4 & 7;
        vfloat4 v;
        v.x = s_tile[ch * 33 + k4 * 4 + 0];
        v.y = s_tile[ch * 33 + k4 * 4 + 1];
        v.z = s_tile[ch * 33 + k4 * 4 + 2];
        v.w = s_tile[ch * 33 + k4 * 4 + 3];
        __builtin_nontemporal_store(v, &of4[((size_t)(b * CH + ch) * NPOINT + j) * 8 + k4]);
    }
}

// ---------------------------------------------------------------------------
// Fallback (small workspace): linear-scan fused kernel, no grid, no transpose.
// ---------------------------------------------------------------------------
__global__ __launch_bounds__(64) void qg_wave_kernel(
    const float* __restrict__ xyz,
    const float* __restrict__ new_xyz,
    const float* __restrict__ feat,      // (B,C,N) original layout
    float* __restrict__ out_cnt,
    float* __restrict__ out_feat)
{
    const int q = blockIdx.x;
    const int b = q >> 11;
    const int j = q & (NPOINT - 1);
    const int l = threadIdx.x;

    __shared__ int   s_idx[NSAMPLE];
    __shared__ float s_tile[CH * 33];

    const float qx = new_xyz[q * 3 + 0];
    const float qy = new_xyz[q * 3 + 1];
    const float qz = new_xyz[q * 3 + 2];
    const float* xb = xyz + (size_t)b * N * 3;

    int cnt = 0;
    for (int base = 0; base < N; base += 64) {
        const int p = base + l;
        const float dx = xb[p * 3 + 0] - qx;
        const float dy = xb[p * 3 + 1] - qy;
        const float dz = xb[p * 3 + 2] - qz;
        const float d2 = dx * dx + dy * dy + dz * dz;
        const bool in = d2 < RADIUS2;
        const unsigned long long m = __ballot(in);
        if (in) {
            const int slot = cnt + __popcll(m & ((1ull << l) - 1ull));
            if (slot < NSAMPLE) s_idx[slot] = p;
        }
        cnt += __popcll(m);
        if (cnt >= NSAMPLE) break;
    }
    if (cnt > NSAMPLE) cnt = NSAMPLE;

    if (l == 0) out_cnt[q] = (float)cnt;
    __syncthreads();
    if (l < NSAMPLE && l >= cnt) s_idx[l] = (cnt > 0) ? s_idx[0] : 0;
    __syncthreads();

    #pragma unroll
    for (int p = 0; p < 8; ++p) {
        const int k  = p * 4 + (l >> 4);
        const int c4 = l & 15;
        const int i  = s_idx[k];
        #pragma unroll
        for (int cc = 0; cc < 4; ++cc) {
            const int c = c4 * 4 + cc;
            s_tile[(3 + c) * 33 + k] = feat[((size_t)b * C + c) * N + i];
        }
    }
    if (l < NSAMPLE) {
        const int i = s_idx[l];
        const float* xp = xyz + ((size_t)b * N + i) * 3;
        s_tile[0 * 33 + l] = xp[0] - qx;
        s_tile[1 * 33 + l] = xp[1] - qy;
        s_tile[2 * 33 + l] = xp[2] - qz;
    }
    __syncthreads();

    float4* of4 = (float4*)out_feat;
    for (int e4 = l; e4 < CH * 8; e4 += 64) {
        const int ch = e4 >> 3;
        const int k4 = e4 & 7;
        float4 v;
        v.x = s_tile[ch * 33 + k4 * 4 + 0];
        v.y = s_tile[ch * 33 + k4 * 4 + 1];
        v.z = s_tile[ch * 33 + k4 * 4 + 2];
        v.w = s_tile[ch * 33 + k4 * 4 + 3];
        of4[((size_t)(b * CH + ch) * NPOINT + j) * 8 + k4] = v;
    }
}

extern "C" void kernel_launch(void* const* d_in, const int* in_sizes, int n_in,
                              void* d_out, int out_size, void* d_ws, size_t ws_size,
                              hipStream_t stream) {
    const float* xyz      = (const float*)d_in[0];   // (B,N,3)
    const float* new_xyz  = (const float*)d_in[1];   // (B,NPOINT,3)
    const float* features = (const float*)d_in[2];   // (B,C,N)

    float* out_cnt  = (float*)d_out;                 // B*NPOINT
    float* out_feat = out_cnt + (size_t)B * NPOINT;  // (B,CH,NPOINT,NSAMPLE)

    char* ws = (char*)d_ws;
    const size_t ftB = (size_t)B * N * C * sizeof(float);   // 16 MB
    const size_t spB = (size_t)B * N * sizeof(float4);      // 4 MB
    const size_t csB = (size_t)B * CSTRIDE * sizeof(int);   // 16.5 KB
    const size_t need = ftB + spB + csB;

    if (ws_size >= need) {
        float*  ft = (float*)ws;
        float4* sp = (float4*)(ws + ftB);
        int*    cs = (int*)(ws + ftB + spB);
        prep_kernel<<<B + B * (N / 64), 256, 0, stream>>>(xyz, features, ft, cs, sp);
        qg_kernel<<<B * NPOINT / 4, 256, 0, stream>>>(xyz, new_xyz, ft, cs, sp,
                                                      out_cnt, out_feat);
    } else {
        qg_wave_kernel<<<B * NPOINT, 64, 0, stream>>>(xyz, new_xyz, features,
                                                      out_cnt, out_feat);
    }
}

// Round 7
// 137.706 us; speedup vs baseline: 1.1737x; 1.1737x over previous
//
#include <hip/hip_runtime.h>

#define B        4
#define N        16384       // 2^14
#define NPOINT   2048        // 2^11
#define C        64
#define NSAMPLE  32
#define CH       (C + 3)     // 67 output channels
#define RADIUS2  0.01f
#define NCELL    1000        // 10^3 cells per batch (cell size = radius)
#define CSTRIDE  1032        // cell_start row stride (ints) >= NCELL+1
#define CCSTRIDE 1024        // counter row stride (ints)
#define CAP      192         // per-query candidate cap (mean ~68, ~15 sigma)

__device__ __forceinline__ int clamp10(int v) {
    return v < 0 ? 0 : (v > 9 ? 9 : v);
}

// ---------------------------------------------------------------------------
// k1: fused transpose + count. Disjoint block ranges, both fully parallel.
//   blocks 0..1023    : transpose tile (B,C,N)->(B,N,C), float4 both ways
//   blocks 1024..1279 : per-cell histogram via global atomics (cc pre-zeroed
//                       by a hipMemsetAsync node before this kernel)
// grid = 1280, block = 256
// ---------------------------------------------------------------------------
__global__ __launch_bounds__(256) void transpose_count_kernel(
    const float* __restrict__ xyz,   // (B,N,3)
    const float* __restrict__ f,     // (B,C,N)
    float* __restrict__ ft,          // (B,N,C)
    int* __restrict__ cc)            // (B, CCSTRIDE) counters (zeroed)
{
    const int t = threadIdx.x;

    if (blockIdx.x >= 1024) {
        const int g = (blockIdx.x - 1024) * 256 + t;    // < B*N = 65536
        const int b = g >> 14;
        const float x = xyz[g * 3 + 0], y = xyz[g * 3 + 1], z = xyz[g * 3 + 2];
        const int cx = clamp10((int)(x * 10.f));
        const int cy = clamp10((int)(y * 10.f));
        const int cz = clamp10((int)(z * 10.f));
        atomicAdd(&cc[(b << 10) + (cx * 10 + cy) * 10 + cz], 1);
        return;
    }

    const int tt = blockIdx.x;           // 0..1023
    const int b  = tt >> 8;              // 256 tiles per batch
    const int n0 = (tt & 255) * 64;

    __shared__ float tile[64][65];
    const int r16 = t >> 4;              // 0..15
    const int x4  = t & 15;              // 0..15
    #pragma unroll
    for (int it = 0; it < 4; ++it) {
        const int cch = it * 16 + r16;
        const float4 v = *(const float4*)(f + ((size_t)b * C + cch) * N + n0 + x4 * 4);
        tile[cch][x4 * 4 + 0] = v.x;
        tile[cch][x4 * 4 + 1] = v.y;
        tile[cch][x4 * 4 + 2] = v.z;
        tile[cch][x4 * 4 + 3] = v.w;
    }
    __syncthreads();
    #pragma unroll
    for (int it = 0; it < 4; ++it) {
        const int nn = it * 16 + r16;
        float4 v;
        v.x = tile[x4 * 4 + 0][nn];
        v.y = tile[x4 * 4 + 1][nn];
        v.z = tile[x4 * 4 + 2][nn];
        v.w = tile[x4 * 4 + 3][nn];
        *(float4*)(ft + ((size_t)b * N + n0 + nn) * C + x4 * 4) = v;
    }
}

// ---------------------------------------------------------------------------
// k2: exclusive scan (1000 cells/batch). grid = B, block = 1024.
// Writes cell_start[0..1000]; re-inits cc[] as the scatter cursor.
// ---------------------------------------------------------------------------
__global__ __launch_bounds__(1024) void prefix_kernel(int* __restrict__ cnt,
                                                      int* __restrict__ cs) {
    __shared__ int s[1024];
    const int t = threadIdx.x, b = blockIdx.x;
    const int v = (t < NCELL) ? cnt[(b << 10) + t] : 0;
    s[t] = v;
    __syncthreads();
    for (int off = 1; off < 1024; off <<= 1) {
        const int u = (t >= off) ? s[t - off] : 0;
        __syncthreads();
        s[t] += u;
        __syncthreads();
    }
    const int excl = (t == 0) ? 0 : s[t - 1];
    if (t <= NCELL) cs[b * CSTRIDE + t] = excl;
    if (t < NCELL)  cnt[(b << 10) + t] = excl;
}

// ---------------------------------------------------------------------------
// k3: scatter points to cell-sorted float4(x,y,z,bitcast(index)). 256 blocks.
// ---------------------------------------------------------------------------
__global__ __launch_bounds__(256) void scatter_kernel(const float* __restrict__ xyz,
                                                      int* __restrict__ cursor,
                                                      float4* __restrict__ sp) {
    const int g = blockIdx.x * 256 + threadIdx.x;
    const int b = g >> 14;
    const int n = g & (N - 1);
    const float x = xyz[g * 3 + 0], y = xyz[g * 3 + 1], z = xyz[g * 3 + 2];
    const int cx = clamp10((int)(x * 10.f));
    const int cy = clamp10((int)(y * 10.f));
    const int cz = clamp10((int)(z * 10.f));
    const int cell = (cx * 10 + cy) * 10 + cz;
    const int pos = atomicAdd(&cursor[(b << 10) + cell], 1);
    sp[(b << 14) + pos] = make_float4(x, y, z, __int_as_float(n));
}

// ---------------------------------------------------------------------------
// k4: fused ball query + grouping. One wave per query, 4 queries per block.
// LDS only 3.6KB/block -> launch_bounds(256,8) -> 8 blocks/CU = 32 waves/CU.
//   Query: order-free flattened scan of the 9 z-runs (bounds in SGPRs via
//          readlane), ballot-append candidates, rank-select restores index
//          order. Wave-private LDS -> __threadfence_block() only.
//   Group: NO LDS tile. k = lane&31 is pass-invariant -> each lane keeps its
//          row pointer; 32 scalar-gather passes, each storing 2 channels as
//          two 128B coalesced segments (lanes 0..31 ch c, 32..63 ch c+1).
// ---------------------------------------------------------------------------
__global__ __launch_bounds__(256, 8) void qg_kernel(
    const float*  __restrict__ xyz,      // (B,N,3)
    const float*  __restrict__ new_xyz,  // (B,NPOINT,3)
    const float*  __restrict__ ft,       // (B,N,C)
    const int*    __restrict__ cs,       // cell starts
    const float4* __restrict__ sp,       // cell-sorted points
    float* __restrict__ out_cnt,         // B*NPOINT
    float* __restrict__ out_feat)        // (B,CH,NPOINT,NSAMPLE)
{
    const int w = threadIdx.x >> 6;      // wave 0..3
    const int l = threadIdx.x & 63;
    const int q = blockIdx.x * 4 + w;    // 0..B*NPOINT-1
    const int b = q >> 11;
    const int j = q & (NPOINT - 1);

    __shared__ int cand_s[4][CAP];
    __shared__ int sidx_s[4][NSAMPLE];
    int* cand  = cand_s[w];
    int* s_idx = sidx_s[w];

    const float qx = new_xyz[q * 3 + 0];
    const float qy = new_xyz[q * 3 + 1];
    const float qz = new_xyz[q * 3 + 2];

    const int cx = clamp10((int)(qx * 10.f));
    const int cy = clamp10((int)(qy * 10.f));
    const int cz = clamp10((int)(qz * 10.f));
    const int z0 = cz > 0 ? cz - 1 : 0;
    const int z1 = cz < 9 ? cz + 1 : 9;

    // lanes 0..8 fetch the 9 run bounds (3x3 xy-cells, z contiguous)
    int sv = 0, ev = 0;
    if (l < 9) {
        const int xx = cx - 1 + l / 3;
        const int yy = cy - 1 + l % 3;
        if (xx >= 0 && xx <= 9 && yy >= 0 && yy <= 9) {
            const int cb = (xx * 10 + yy) * 10;
            sv = cs[b * CSTRIDE + cb + z0];
            ev = cs[b * CSTRIDE + cb + z1 + 1];
        }
    }
    const int len = ev - sv;

    // hoist run starts/lengths into uniform (SGPR) values
    int S[9], L[9];
    #pragma unroll
    for (int r = 0; r < 9; ++r) {
        S[r] = __builtin_amdgcn_readlane(sv, r);
        L[r] = __builtin_amdgcn_readlane(len, r);
    }
    int T = 0;
    #pragma unroll
    for (int r = 0; r < 9; ++r) T += L[r];

    const unsigned long long ltmask = (1ull << l) - 1ull;
    int total = 0, ncand = 0;
    for (int base = 0; base < T; base += 64) {
        const int wid = base + l;
        int p = 0, acc = 0;
        bool act = false;
        #pragma unroll
        for (int r = 0; r < 9; ++r) {
            const int off = wid - acc;
            if (off >= 0 && off < L[r]) { p = S[r] + off; act = true; }
            acc += L[r];
        }
        float4 pt = make_float4(1e9f, 1e9f, 1e9f, 0.f);
        if (act) pt = sp[(b << 14) + p];
        const float dx = pt.x - qx, dy = pt.y - qy, dz = pt.z - qz;
        const float d2 = dx * dx + dy * dy + dz * dz;
        const bool in = act && (d2 < RADIUS2);
        const unsigned long long m = __ballot(in);
        if (in) {
            const int slot = ncand + __popcll(m & ltmask);
            if (slot < CAP) cand[slot] = __float_as_int(pt.w);
        }
        const int c = __popcll(m);
        total += c;
        ncand = ncand + c > CAP ? CAP : ncand + c;
    }

    int cntv;
    if (total > CAP) {
        // overflow (astronomically unlikely for uniform data): ordered rescan
        const float* xb = xyz + (size_t)b * N * 3;
        int cnt2 = 0;
        for (int base = 0; base < N; base += 64) {
            const int p = base + l;
            const float dx = xb[p * 3 + 0] - qx;
            const float dy = xb[p * 3 + 1] - qy;
            const float dz = xb[p * 3 + 2] - qz;
            const float d2 = dx * dx + dy * dy + dz * dz;
            const bool in = d2 < RADIUS2;
            const unsigned long long m = __ballot(in);
            if (in) {
                const int slot = cnt2 + __popcll(m & ltmask);
                if (slot < NSAMPLE) s_idx[slot] = p;
            }
            cnt2 += __popcll(m);
            if (cnt2 >= NSAMPLE) break;
        }
        cntv = cnt2 < NSAMPLE ? cnt2 : NSAMPLE;
        __threadfence_block();
    } else {
        __threadfence_block();           // cand[] appends visible to wave
        const int K = ncand;             // == total
        for (int c = l; c < K; c += 64) {
            const int v = cand[c];
            int rnk = 0;
            for (int i = 0; i < K; ++i) rnk += (cand[i] < v) ? 1 : 0;
            if (rnk < NSAMPLE) s_idx[rnk] = v;   // first-32 in index order
        }
        cntv = total < NSAMPLE ? total : NSAMPLE;
        __threadfence_block();
    }

    // fill unfound slots with first index (0 if none)
    if (l < NSAMPLE && l >= cntv) s_idx[l] = (cntv > 0) ? s_idx[0] : 0;
    __threadfence_block();

    if (l == 0) out_cnt[q] = (float)cntv;

    // ---- direct gather + store (no LDS tile, no barrier) ----
    const int k   = l & 31;              // pass-invariant slot
    const int i   = s_idx[k];
    const int chh = l >> 5;              // 0 or 1: which channel of the pair

    // xyz channels 0..2 (lanes 0..31; one 128B segment per channel)
    if (l < 32) {
        const float* xp = xyz + ((size_t)b * N + i) * 3;
        float* ob = out_feat + ((size_t)(b * CH) * NPOINT + j) * NSAMPLE + l;
        __builtin_nontemporal_store(xp[0] - qx, ob);
        __builtin_nontemporal_store(xp[1] - qy, ob + NPOINT * NSAMPLE);
        __builtin_nontemporal_store(xp[2] - qz, ob + 2 * NPOINT * NSAMPLE);
    }
    // feature channels 3..66: pass p covers ch = 3 + 2p + chh
    const float* fp = ft + ((size_t)b * N + i) * C + chh;
    float* op = out_feat + ((size_t)(b * CH + 3 + chh) * NPOINT + j) * NSAMPLE + k;
    #pragma unroll 8
    for (int p = 0; p < 32; ++p) {
        __builtin_nontemporal_store(fp[2 * p],
                                    op + (size_t)2 * p * NPOINT * NSAMPLE);
    }
}

// ---------------------------------------------------------------------------
// Fallback (small workspace): linear-scan fused kernel, no grid, no transpose.
// ---------------------------------------------------------------------------
__global__ __launch_bounds__(64) void qg_wave_kernel(
    const float* __restrict__ xyz,
    const float* __restrict__ new_xyz,
    const float* __restrict__ feat,      // (B,C,N) original layout
    float* __restrict__ out_cnt,
    float* __restrict__ out_feat)
{
    const int q = blockIdx.x;
    const int b = q >> 11;
    const int j = q & (NPOINT - 1);
    const int l = threadIdx.x;

    __shared__ int s_idx[NSAMPLE];

    const float qx = new_xyz[q * 3 + 0];
    const float qy = new_xyz[q * 3 + 1];
    const float qz = new_xyz[q * 3 + 2];
    const float* xb = xyz + (size_t)b * N * 3;

    int cnt = 0;
    for (int base = 0; base < N; base += 64) {
        const int p = base + l;
        const float dx = xb[p * 3 + 0] - qx;
        const float dy = xb[p * 3 + 1] - qy;
        const float dz = xb[p * 3 + 2] - qz;
        const float d2 = dx * dx + dy * dy + dz * dz;
        const bool in = d2 < RADIUS2;
        const unsigned long long m = __ballot(in);
        if (in) {
            const int slot = cnt + __popcll(m & ((1ull << l) - 1ull));
            if (slot < NSAMPLE) s_idx[slot] = p;
        }
        cnt += __popcll(m);
        if (cnt >= NSAMPLE) break;
    }
    if (cnt > NSAMPLE) cnt = NSAMPLE;

    if (l == 0) out_cnt[q] = (float)cnt;
    __syncthreads();
    if (l < NSAMPLE && l >= cnt) s_idx[l] = (cnt > 0) ? s_idx[0] : 0;
    __syncthreads();

    const int k   = l & 31;
    const int i   = s_idx[k];
    const int chh = l >> 5;
    if (l < 32) {
        const float* xp = xyz + ((size_t)b * N + i) * 3;
        float* ob = out_feat + ((size_t)(b * CH) * NPOINT + j) * NSAMPLE + l;
        ob[0]                   = xp[0] - qx;
        ob[NPOINT * NSAMPLE]     = xp[1] - qy;
        ob[2 * NPOINT * NSAMPLE] = xp[2] - qz;
    }
    const float* fp = feat + ((size_t)b * C + chh) * N + i;   // (B,C,N) layout
    float* op = out_feat + ((size_t)(b * CH + 3 + chh) * NPOINT + j) * NSAMPLE + k;
    #pragma unroll 8
    for (int p = 0; p < 32; ++p) {
        op[(size_t)2 * p * NPOINT * NSAMPLE] = fp[(size_t)2 * p * N];
    }
}

extern "C" void kernel_launch(void* const* d_in, const int* in_sizes, int n_in,
                              void* d_out, int out_size, void* d_ws, size_t ws_size,
                              hipStream_t stream) {
    const float* xyz      = (const float*)d_in[0];   // (B,N,3)
    const float* new_xyz  = (const float*)d_in[1];   // (B,NPOINT,3)
    const float* features = (const float*)d_in[2];   // (B,C,N)

    float* out_cnt  = (float*)d_out;                 // B*NPOINT
    float* out_feat = out_cnt + (size_t)B * NPOINT;  // (B,CH,NPOINT,NSAMPLE)

    char* ws = (char*)d_ws;
    const size_t ftB = (size_t)B * N * C * sizeof(float);     // 16 MB
    const size_t spB = (size_t)B * N * sizeof(float4);        // 4 MB
    const size_t csB = (size_t)B * CSTRIDE * sizeof(int);
    const size_t ccB = (size_t)B * CCSTRIDE * sizeof(int);
    const size_t need = ftB + spB + csB + ccB;

    if (ws_size >= need) {
        float*  ft = (float*)ws;
        float4* sp = (float4*)(ws + ftB);
        int*    cs = (int*)(ws + ftB + spB);
        int*    cc = (int*)(ws + ftB + spB + csB);
        hipMemsetAsync(cc, 0, ccB, stream);   // legal graph memset node
        transpose_count_kernel<<<1280, 256, 0, stream>>>(xyz, features, ft, cc);
        prefix_kernel<<<B, 1024, 0, stream>>>(cc, cs);
        scatter_kernel<<<B * N / 256, 256, 0, stream>>>(xyz, cc, sp);
        qg_kernel<<<B * NPOINT / 4, 256, 0, stream>>>(xyz, new_xyz, ft, cs, sp,
                                                      out_cnt, out_feat);
    } else {
        qg_wave_kernel<<<B * NPOINT, 64, 0, stream>>>(xyz, new_xyz, features,
                                                      out_cnt, out_feat);
    }
}